// Round 1
// baseline (1576.665 us; speedup 1.0000x reference)
//
#include <hip/hip_runtime.h>
#include <cmath>

#define HW_ 16384
#define IMG_W 128
#define IMG_H 128
#define DIM_ 256
#define D3_ 768
#define HEADS_ 4
#define C_ 64
#define B_ 8

// ---------------------------------------------------------------------------
// K1: fused conv1x1 GEMM. Output rows 0..767 -> qkv_raw, rows 768..895 ->
// gate hidden g1 = relu(W1 x + b1). Tiled 128x128, K=256 in 16-step tiles,
// 256 threads, 8x8 per thread (split 4+4 rows/cols for LDS broadcast reads).
// ---------------------------------------------------------------------------
__global__ __launch_bounds__(256, 2) void k1_gemm(
    const float* __restrict__ x, const float* __restrict__ w_qkv,
    const float* __restrict__ gw1, const float* __restrict__ gb1,
    float* __restrict__ qkvraw, float* __restrict__ g1, int bbase)
{
  const int t = threadIdx.x;
  const int cb = blockIdx.x, rb = blockIdx.y, s = blockIdx.z;
  const int b = bbase + s;
  const int row0 = rb * 128, col0 = cb * 128;

  __shared__ float As[16][128];
  __shared__ float Bs[16][132];

  const int lm = t >> 1;
  const int lkg = (t & 1) << 3;
  const int grow_l = row0 + lm;
  const float* Arow = (grow_l < 768) ? (w_qkv + (size_t)grow_l * DIM_)
                                     : (gw1 + (size_t)(grow_l - 768) * DIM_);
  const int lkx = t >> 4;
  const int lng = (t & 15) << 3;
  const float* Xp = x + (size_t)b * DIM_ * HW_ + col0 + lng;

  const int tn = t & 15, tm = t >> 4;

  float acc[8][8];
#pragma unroll
  for (int i = 0; i < 8; ++i)
#pragma unroll
    for (int j = 0; j < 8; ++j) acc[i][j] = 0.f;

  float4 ra0 = *(const float4*)(Arow + lkg);
  float4 ra1 = *(const float4*)(Arow + lkg + 4);
  float4 rb0 = *(const float4*)(Xp + (size_t)lkx * HW_);
  float4 rb1 = *(const float4*)(Xp + (size_t)lkx * HW_ + 4);

  for (int kt = 0; kt < 16; ++kt) {
    __syncthreads();
    As[lkg + 0][lm] = ra0.x; As[lkg + 1][lm] = ra0.y;
    As[lkg + 2][lm] = ra0.z; As[lkg + 3][lm] = ra0.w;
    As[lkg + 4][lm] = ra1.x; As[lkg + 5][lm] = ra1.y;
    As[lkg + 6][lm] = ra1.z; As[lkg + 7][lm] = ra1.w;
    *(float4*)&Bs[lkx][lng] = rb0;
    *(float4*)&Bs[lkx][lng + 4] = rb1;
    __syncthreads();
    if (kt < 15) {
      const int k0 = (kt + 1) * 16;
      ra0 = *(const float4*)(Arow + k0 + lkg);
      ra1 = *(const float4*)(Arow + k0 + lkg + 4);
      rb0 = *(const float4*)(Xp + (size_t)(k0 + lkx) * HW_);
      rb1 = *(const float4*)(Xp + (size_t)(k0 + lkx) * HW_ + 4);
    }
#pragma unroll
    for (int k = 0; k < 16; ++k) {
      const float4 a0 = *(const float4*)&As[k][tm * 4];
      const float4 a1 = *(const float4*)&As[k][64 + tm * 4];
      const float4 b0 = *(const float4*)&Bs[k][tn * 4];
      const float4 b1 = *(const float4*)&Bs[k][64 + tn * 4];
      const float av[8] = {a0.x, a0.y, a0.z, a0.w, a1.x, a1.y, a1.z, a1.w};
      const float bv[8] = {b0.x, b0.y, b0.z, b0.w, b1.x, b1.y, b1.z, b1.w};
#pragma unroll
      for (int i = 0; i < 8; ++i)
#pragma unroll
        for (int j = 0; j < 8; ++j) acc[i][j] += av[i] * bv[j];
    }
  }

#pragma unroll
  for (int i = 0; i < 8; ++i) {
    const int m = (i < 4) ? (tm * 4 + i) : (64 + tm * 4 + (i - 4));
    const int grow = row0 + m;
#pragma unroll
    for (int jg = 0; jg < 2; ++jg) {
      const int n = col0 + jg * 64 + tn * 4;
      float4 v;
      v.x = acc[i][jg * 4 + 0]; v.y = acc[i][jg * 4 + 1];
      v.z = acc[i][jg * 4 + 2]; v.w = acc[i][jg * 4 + 3];
      if (grow < 768) {
        *(float4*)(qkvraw + ((size_t)s * D3_ + grow) * HW_ + n) = v;
      } else {
        const int r = grow - 768;
        const float bb = gb1[r];
        v.x = fmaxf(v.x + bb, 0.f); v.y = fmaxf(v.y + bb, 0.f);
        v.z = fmaxf(v.z + bb, 0.f); v.w = fmaxf(v.w + bb, 0.f);
        *(float4*)(g1 + ((size_t)s * 128 + r) * HW_ + n) = v;
      }
    }
  }
}

// ---------------------------------------------------------------------------
// K2: gate second layer: per-pixel sigmoid(w2 . g1 + b2), block-sum partials.
// ---------------------------------------------------------------------------
__global__ __launch_bounds__(256) void k2_gate(
    const float* __restrict__ g1, const float* __restrict__ w2,
    const float* __restrict__ b2, float* __restrict__ gpart, int bbase)
{
  const int t = threadIdx.x;
  const int blk = blockIdx.x;   // 0..63
  const int s = blockIdx.y;
  const int b = bbase + s;
  const int p = blk * 256 + t;
  const float* gp = g1 + (size_t)s * 128 * HW_ + p;
  float sv = b2[0];
#pragma unroll 8
  for (int c = 0; c < 128; ++c) sv += gp[(size_t)c * HW_] * w2[c];
  const float sig = 1.f / (1.f + expf(-sv));
  __shared__ float red[256];
  red[t] = sig;
  __syncthreads();
  for (int o = 128; o > 0; o >>= 1) {
    if (t < o) red[t] += red[t + o];
    __syncthreads();
  }
  if (t == 0) gpart[b * 64 + blk] = red[0];
}

// ---------------------------------------------------------------------------
// K3a: depthwise 3x3 (cross-correlation, SAME zero pad). 8-row tiles.
// q,k channels -> ws (+ per-block sum of squares partial); v -> d_out.
// ---------------------------------------------------------------------------
__global__ __launch_bounds__(256) void k3a_dw(
    const float* __restrict__ qkvraw, const float* __restrict__ wdw,
    float* __restrict__ qdw, float* __restrict__ kdw, float* __restrict__ vout,
    float* __restrict__ ssq_part, int bbase)
{
  const int t = threadIdx.x;
  const int ytile = blockIdx.x;  // 0..15
  const int ch = blockIdx.y;     // 0..767
  const int s = blockIdx.z;
  const int b = bbase + s;
  const int y0 = ytile * 8;

  __shared__ float sm[10][130];
  const float* in = qkvraw + ((size_t)s * D3_ + ch) * HW_;
  for (int i = t; i < 1300; i += 256) {
    const int r = i / 130;
    const int xx = i - r * 130 - 1;
    const int row = y0 - 1 + r;
    float v = 0.f;
    if (row >= 0 && row < IMG_H && xx >= 0 && xx < IMG_W)
      v = in[row * IMG_W + xx];
    sm[r][i - r * 130] = v;
  }
  const float* wp = wdw + ch * 9;
  const float w00 = wp[0], w01 = wp[1], w02 = wp[2],
              w10 = wp[3], w11 = wp[4], w12 = wp[5],
              w20 = wp[6], w21 = wp[7], w22 = wp[8];
  __syncthreads();

  float* outp;
  if (ch < 256)       outp = qdw + ((size_t)s * 256 + ch) * HW_;
  else if (ch < 512)  outp = kdw + ((size_t)s * 256 + (ch - 256)) * HW_;
  else                outp = vout + ((size_t)b * DIM_ + (ch - 512)) * HW_;

  float sq = 0.f;
#pragma unroll
  for (int it = 0; it < 4; ++it) {
    const int px = t + it * 256;
    const int yl = px >> 7, xx = px & 127;
    const float a =
      w00 * sm[yl][xx]     + w01 * sm[yl][xx + 1]     + w02 * sm[yl][xx + 2] +
      w10 * sm[yl + 1][xx] + w11 * sm[yl + 1][xx + 1] + w12 * sm[yl + 1][xx + 2] +
      w20 * sm[yl + 2][xx] + w21 * sm[yl + 2][xx + 1] + w22 * sm[yl + 2][xx + 2];
    outp[y0 * IMG_W + px] = a;
    sq += a * a;
  }

  if (ch < 512) {
    __shared__ float red[256];
    red[t] = sq;
    __syncthreads();
    for (int o = 128; o > 0; o >>= 1) {
      if (t < o) red[t] += red[t + o];
      __syncthreads();
    }
    if (t == 0) ssq_part[((size_t)b * 512 + ch) * 16 + ytile] = red[0];
  }
}

// ---------------------------------------------------------------------------
// K3b: Gram partials S[c,d] = sum_p q[c,p] k[d,p] over a 256-pixel chunk.
// 256 threads, 4x4 micro-tile, LDS tiles transposed [px][c] (pad 68).
// ---------------------------------------------------------------------------
__global__ __launch_bounds__(256) void k3b_gram(
    const float* __restrict__ qdw, const float* __restrict__ kdw,
    float* __restrict__ S_part, int bbase)
{
  const int t = threadIdx.x;
  const int chunk = blockIdx.x;  // 0..63
  const int h = blockIdx.y;
  const int s = blockIdx.z;
  const int b = bbase + s;
  const int p0 = chunk * 256;

  __shared__ float qs[64][68];
  __shared__ float ks[64][68];

  const int rc = t >> 4, dc = t & 15;

  float acc[4][4];
#pragma unroll
  for (int i = 0; i < 4; ++i)
#pragma unroll
    for (int j = 0; j < 4; ++j) acc[i][j] = 0.f;

  const float* qbase = qdw + ((size_t)s * 256 + h * 64) * HW_ + p0;
  const float* kbase = kdw + ((size_t)s * 256 + h * 64) * HW_ + p0;

  for (int kk = 0; kk < 256; kk += 64) {
    __syncthreads();
#pragma unroll
    for (int j = 0; j < 4; ++j) {
      const int lin = t + j * 256;
      const int c = lin >> 4;
      const int px0 = (lin & 15) << 2;
      const float4 qv = *(const float4*)(qbase + (size_t)c * HW_ + kk + px0);
      const float4 kv = *(const float4*)(kbase + (size_t)c * HW_ + kk + px0);
      qs[px0 + 0][c] = qv.x; qs[px0 + 1][c] = qv.y;
      qs[px0 + 2][c] = qv.z; qs[px0 + 3][c] = qv.w;
      ks[px0 + 0][c] = kv.x; ks[px0 + 1][c] = kv.y;
      ks[px0 + 2][c] = kv.z; ks[px0 + 3][c] = kv.w;
    }
    __syncthreads();
#pragma unroll 4
    for (int p = 0; p < 64; ++p) {
      const float4 q4 = *(const float4*)&qs[p][rc * 4];
      const float4 k4 = *(const float4*)&ks[p][dc * 4];
      const float qa[4] = {q4.x, q4.y, q4.z, q4.w};
      const float ka[4] = {k4.x, k4.y, k4.z, k4.w};
#pragma unroll
      for (int i = 0; i < 4; ++i)
#pragma unroll
        for (int jj = 0; jj < 4; ++jj) acc[i][jj] += qa[i] * ka[jj];
    }
  }
  float* op = S_part + (((size_t)(b * HEADS_ + h)) * 64 + chunk) * 4096;
#pragma unroll
  for (int i = 0; i < 4; ++i) {
    float4 v;
    v.x = acc[i][0]; v.y = acc[i][1]; v.z = acc[i][2]; v.w = acc[i][3];
    *(float4*)(op + (rc * 4 + i) * 64 + dc * 4) = v;
  }
}

// ---------------------------------------------------------------------------
// K4: finalize attention. One wave per (b,h). Sums partials, computes norms,
// dk from gate mean, per-row rank-based top-k mask, masked softmax.
// ---------------------------------------------------------------------------
__global__ __launch_bounds__(64) void k4_final(
    const float* __restrict__ S_part, const float* __restrict__ ssq_part,
    const float* __restrict__ gpart, const float* __restrict__ temperature,
    float* __restrict__ attn)
{
  const int d = threadIdx.x;   // 0..63
  const int bh = blockIdx.x;   // 0..31
  const int b = bh >> 2, h = bh & 3;

  float gs = 0.f;
  for (int i = 0; i < 512; ++i) gs += gpart[i];
  const float mean = gs / (float)((size_t)B_ * HW_);
  int dk = (int)floorf((float)C_ * mean);
  dk = min(max(dk, 1), 64);

  __shared__ float Ss[64 * 64];
  __shared__ float invq_s[64], invk_s[64];

  {
    float sq = 0.f, sk = 0.f;
    const size_t qb = ((size_t)b * 512 + h * 64 + d) * 16;
    const size_t kb = ((size_t)b * 512 + 256 + h * 64 + d) * 16;
    for (int yt = 0; yt < 16; ++yt) { sq += ssq_part[qb + yt]; sk += ssq_part[kb + yt]; }
    invq_s[d] = 1.f / fmaxf(sqrtf(sq), 1e-12f);
    invk_s[d] = 1.f / fmaxf(sqrtf(sk), 1e-12f);
  }

  const float* Sp = S_part + ((size_t)(b * HEADS_ + h)) * 64 * 4096;
  for (int c = 0; c < 64; ++c) {
    float acc = 0.f;
    for (int ch = 0; ch < 64; ++ch) acc += Sp[(size_t)ch * 4096 + c * 64 + d];
    Ss[c * 64 + d] = acc;
  }
  __syncthreads();

  const float tval = temperature[h];
  float* op = attn + (size_t)bh * 4096;
  for (int c = 0; c < 64; ++c) {
    const float val = Ss[c * 64 + d] * invq_s[c] * invk_s[d] * tval;
    int rank = 0;
    for (int i = 0; i < 64; ++i) {
      const float vi = __shfl(val, i, 64);
      rank += ((vi > val) || (vi == val && i < d)) ? 1 : 0;
    }
    const bool keep = rank < dk;
    float mv = keep ? val : -INFINITY;
#pragma unroll
    for (int m = 1; m < 64; m <<= 1) mv = fmaxf(mv, __shfl_xor(mv, m, 64));
    const float e = keep ? expf(val - mv) : 0.f;
    float ssum = e;
#pragma unroll
    for (int m = 1; m < 64; m <<= 1) ssum += __shfl_xor(ssum, m, 64);
    op[c * 64 + d] = e / ssum;
  }
}

// ---------------------------------------------------------------------------
// K5: out = (a1+a2+a3+a4) * attn @ v, in place on d_out (v lives there).
// Each thread owns 2 pixel columns: reads all 64 v values first, then writes.
// ---------------------------------------------------------------------------
__global__ __launch_bounds__(256) void k5_av(
    const float* __restrict__ attn, float* __restrict__ out,
    const float* __restrict__ a1, const float* __restrict__ a2,
    const float* __restrict__ a3, const float* __restrict__ a4)
{
  const int t = threadIdx.x;
  const int pc = blockIdx.x;  // 0..31
  const int h = blockIdx.y;
  const int b = blockIdx.z;
  const int p0 = pc * 512;

  __shared__ float As5[4096];
  const float* ap = attn + ((size_t)(b * HEADS_ + h)) * 4096;
#pragma unroll
  for (int j = 0; j < 4; ++j) {
    const int idx = (t + j * 256) * 4;
    *(float4*)&As5[idx] = *(const float4*)(ap + idx);
  }
  const float sc = a1[0] + a2[0] + a3[0] + a4[0];
  float* base = out + ((size_t)b * DIM_ + h * 64) * HW_ + p0;

  float v0[64], v1[64];
#pragma unroll
  for (int dd = 0; dd < 64; ++dd) {
    v0[dd] = base[(size_t)dd * HW_ + t];
    v1[dd] = base[(size_t)dd * HW_ + t + 256];
  }
  __syncthreads();

  for (int c = 0; c < 64; ++c) {
    float acc0 = 0.f, acc1 = 0.f;
#pragma unroll
    for (int d4 = 0; d4 < 16; ++d4) {
      const float4 a = *(const float4*)&As5[c * 64 + d4 * 4];
      acc0 = fmaf(a.x, v0[d4 * 4 + 0], acc0);
      acc0 = fmaf(a.y, v0[d4 * 4 + 1], acc0);
      acc0 = fmaf(a.z, v0[d4 * 4 + 2], acc0);
      acc0 = fmaf(a.w, v0[d4 * 4 + 3], acc0);
      acc1 = fmaf(a.x, v1[d4 * 4 + 0], acc1);
      acc1 = fmaf(a.y, v1[d4 * 4 + 1], acc1);
      acc1 = fmaf(a.z, v1[d4 * 4 + 2], acc1);
      acc1 = fmaf(a.w, v1[d4 * 4 + 3], acc1);
    }
    base[(size_t)c * HW_ + t] = sc * acc0;
    base[(size_t)c * HW_ + t + 256] = sc * acc1;
  }
}

// ---------------------------------------------------------------------------
extern "C" void kernel_launch(void* const* d_in, const int* in_sizes, int n_in,
                              void* d_out, int out_size, void* d_ws, size_t ws_size,
                              hipStream_t stream)
{
  const float* x    = (const float*)d_in[0];
  const float* wqkv = (const float*)d_in[1];
  const float* wdw  = (const float*)d_in[2];
  const float* temp = (const float*)d_in[3];
  const float* a1   = (const float*)d_in[4];
  const float* a2   = (const float*)d_in[5];
  const float* a3   = (const float*)d_in[6];
  const float* a4   = (const float*)d_in[7];
  const float* gw1  = (const float*)d_in[8];
  const float* gb1  = (const float*)d_in[9];
  const float* gw2  = (const float*)d_in[10];
  const float* gb2  = (const float*)d_in[11];
  float* out = (float*)d_out;
  (void)in_sizes; (void)n_in; (void)out_size;

  const size_t HWs = (size_t)HW_;
  const size_t fixedf = (size_t)8 * 4 * 64 * 4096   // S_part
                      + (size_t)8 * 512 * 16        // ssq partials
                      + 512                         // gate partials
                      + (size_t)8 * 4 * 4096;       // attn
  int NB = 8;
  while (NB > 1) {
    const size_t perb = (size_t)D3_ * HWs + 128 * HWs + 2 * (size_t)DIM_ * HWs;
    if ((perb * (size_t)NB + fixedf) * 4 <= ws_size) break;
    NB >>= 1;
  }

  float* ws = (float*)d_ws;
  size_t off = 0;
  float* qkvraw = ws + off; off += (size_t)NB * D3_ * HWs;
  float* g1     = ws + off; off += (size_t)NB * 128 * HWs;
  float* qdw    = ws + off; off += (size_t)NB * DIM_ * HWs;
  float* kdw    = ws + off; off += (size_t)NB * DIM_ * HWs;
  float* S_part = ws + off; off += (size_t)8 * 4 * 64 * 4096;
  float* ssqp   = ws + off; off += (size_t)8 * 512 * 16;
  float* gpart  = ws + off; off += 512;
  float* attnb  = ws + off; off += (size_t)8 * 4 * 4096;

  for (int g = 0; g < B_ / NB; ++g) {
    const int bbase = g * NB;
    k1_gemm<<<dim3(128, 7, NB), 256, 0, stream>>>(x, wqkv, gw1, gb1, qkvraw, g1, bbase);
    k2_gate<<<dim3(64, NB, 1), 256, 0, stream>>>(g1, gw2, gb2, gpart, bbase);
    k3a_dw<<<dim3(16, 768, NB), 256, 0, stream>>>(qkvraw, wdw, qdw, kdw, out, ssqp, bbase);
    k3b_gram<<<dim3(64, 4, NB), 256, 0, stream>>>(qdw, kdw, S_part, bbase);
  }
  k4_final<<<dim3(32), 64, 0, stream>>>(S_part, ssqp, gpart, temp, attnb);
  k5_av<<<dim3(32, 4, 8), 256, 0, stream>>>(attnb, out, a1, a2, a3, a4);
}

// Round 2
// 923.763 us; speedup vs baseline: 1.7068x; 1.7068x over previous
//
#include <hip/hip_runtime.h>
#include <hip/hip_bf16.h>
#include <cmath>

#define HW_ 16384
#define IMG_W 128
#define IMG_H 128
#define DIM_ 256
#define D3_ 768
#define HEADS_ 4
#define C_ 64
#define B_ 8

typedef unsigned short ushort_t;
typedef __attribute__((ext_vector_type(8))) short short8v;
typedef __attribute__((ext_vector_type(16))) float f32x16;

static __device__ __forceinline__ ushort_t f2bf_bits(float v) {
  __hip_bfloat16 h = __float2bfloat16(v);
  return *reinterpret_cast<ushort_t*>(&h);
}

// ---------------------------------------------------------------------------
// K0a: split W (w_qkv rows 0..767, gw1 rows 768..895) into bf16 hi/lo.
// ---------------------------------------------------------------------------
__global__ __launch_bounds__(256) void k0_wsplit(
    const float* __restrict__ wqkv, const float* __restrict__ gw1,
    ushort_t* __restrict__ WH, ushort_t* __restrict__ WL)
{
  const int row = blockIdx.x;
  const int t = threadIdx.x;
  const float* src = (row < 768) ? (wqkv + (size_t)row * DIM_)
                                 : (gw1 + (size_t)(row - 768) * DIM_);
  const float v = src[t];
  const ushort_t hb = f2bf_bits(v);
  __hip_bfloat16 h = *reinterpret_cast<const __hip_bfloat16*>(&hb);
  const float hf = __bfloat162float(h);
  WH[(size_t)row * DIM_ + t] = hb;
  WL[(size_t)row * DIM_ + t] = f2bf_bits(v - hf);
}

// ---------------------------------------------------------------------------
// K0b: transpose+split X[b] [256][16384] -> XtH/XtL [16384][256] bf16.
// Xt lives in the per-slot union region (later overwritten by qdw/kdw).
// ---------------------------------------------------------------------------
__global__ __launch_bounds__(256) void k0_xt(
    const float* __restrict__ x, float* __restrict__ uni, int bbase)
{
  const int t = threadIdx.x;
  const int s = blockIdx.z;
  const int b = bbase + s;
  ushort_t* XtH = (ushort_t*)(uni + (size_t)s * 512 * HW_);
  ushort_t* XtL = XtH + (size_t)DIM_ * HW_;
  const int p0 = blockIdx.x * 32, c0 = blockIdx.y * 32;
  const int tx = t & 31, ty = t >> 5;

  __shared__ float sm[32][33];
#pragma unroll
  for (int i = 0; i < 4; ++i) {
    const int c = c0 + ty + i * 8;
    sm[ty + i * 8][tx] = x[((size_t)b * DIM_ + c) * HW_ + p0 + tx];
  }
  __syncthreads();
#pragma unroll
  for (int i = 0; i < 4; ++i) {
    const int p = p0 + ty + i * 8;
    const float v = sm[tx][ty + i * 8];
    const ushort_t hb = f2bf_bits(v);
    __hip_bfloat16 h = *reinterpret_cast<const __hip_bfloat16*>(&hb);
    const float hf = __bfloat162float(h);
    XtH[(size_t)p * DIM_ + c0 + tx] = hb;
    XtL[(size_t)p * DIM_ + c0 + tx] = f2bf_bits(v - hf);
  }
}

// ---------------------------------------------------------------------------
// K1: MFMA GEMM (bf16 hi/lo split, 3 MFMA per product). C[896][16384] per b.
// Block: 128(m) x 128(n), K=256 in BK=64 stages. 4 waves (2x2), 64x64/wave,
// 2x2 tiles of v_mfma_f32_32x32x16_bf16. LDS 64KB fragment-linear.
// Rows 0..767 -> qkvraw; rows 768..895 -> g1 = relu(.+gb1).
// ---------------------------------------------------------------------------
__global__ __launch_bounds__(256, 2) void k1_mfma(
    const ushort_t* __restrict__ WH, const ushort_t* __restrict__ WL,
    const float* __restrict__ uni, const float* __restrict__ gb1,
    float* __restrict__ qkvraw, float* __restrict__ g1)
{
  const int t = threadIdx.x;
  const int cb = blockIdx.x, rb = blockIdx.y, s = blockIdx.z;
  const int row0 = rb * 128, col0 = cb * 128;
  const ushort_t* XtH = (const ushort_t*)(uni + (size_t)s * 512 * HW_);
  const ushort_t* XtL = XtH + (size_t)DIM_ * HW_;

  __shared__ __align__(16) ushort_t lds[4 * 8192];  // 64 KB
  ushort_t* AH = lds;
  ushort_t* AL = lds + 8192;
  ushort_t* BH = lds + 16384;
  ushort_t* BL = lds + 24576;

  const int lane = t & 63, wid = t >> 6;
  const int wm = wid >> 1, wn = wid & 1;
  const int rr = t & 31, w8 = t >> 5;

  f32x16 acc[2][2];
#pragma unroll
  for (int mi = 0; mi < 2; ++mi)
#pragma unroll
    for (int ni = 0; ni < 2; ++ni)
#pragma unroll
      for (int r = 0; r < 16; ++r) acc[mi][ni][r] = 0.f;

  for (int kt = 0; kt < 4; ++kt) {
    const int k0 = kt * 64;
    __syncthreads();
#pragma unroll
    for (int i = 0; i < 4; ++i) {
      const int koff = k0 + w8 * 8;
      const size_t arow = (size_t)(row0 + i * 32 + rr);
      const short8v a_h = *(const short8v*)(WH + arow * DIM_ + koff);
      const short8v a_l = *(const short8v*)(WL + arow * DIM_ + koff);
      const size_t prow = (size_t)(col0 + i * 32 + rr);
      const short8v b_h = *(const short8v*)(XtH + prow * DIM_ + koff);
      const short8v b_l = *(const short8v*)(XtL + prow * DIM_ + koff);
      const int o = (i * 8 + w8) * 256 + rr * 8;  // chunk-linear, conflict-free
      *(short8v*)(AH + o) = a_h;
      *(short8v*)(AL + o) = a_l;
      *(short8v*)(BH + o) = b_h;
      *(short8v*)(BL + o) = b_l;
    }
    __syncthreads();
    const int lo = lane * 8;  // lane-linear 16B within 1024B chunk-pair
#pragma unroll
    for (int ks = 0; ks < 4; ++ks) {
      short8v ah[2], al[2], bh[2], bl[2];
#pragma unroll
      for (int mi = 0; mi < 2; ++mi) {
        const int base = ((wm * 2 + mi) * 8 + ks * 2) * 256 + lo;
        ah[mi] = *(const short8v*)(AH + base);
        al[mi] = *(const short8v*)(AL + base);
      }
#pragma unroll
      for (int ni = 0; ni < 2; ++ni) {
        const int base = ((wn * 2 + ni) * 8 + ks * 2) * 256 + lo;
        bh[ni] = *(const short8v*)(BH + base);
        bl[ni] = *(const short8v*)(BL + base);
      }
#pragma unroll
      for (int mi = 0; mi < 2; ++mi)
#pragma unroll
        for (int ni = 0; ni < 2; ++ni) {
          acc[mi][ni] = __builtin_amdgcn_mfma_f32_32x32x16_bf16(
              ah[mi], bh[ni], acc[mi][ni], 0, 0, 0);
          acc[mi][ni] = __builtin_amdgcn_mfma_f32_32x32x16_bf16(
              ah[mi], bl[ni], acc[mi][ni], 0, 0, 0);
          acc[mi][ni] = __builtin_amdgcn_mfma_f32_32x32x16_bf16(
              al[mi], bh[ni], acc[mi][ni], 0, 0, 0);
        }
    }
  }

  // Epilogue: C/D layout col=lane&31, row=(reg&3)+8*(reg>>2)+4*(lane>>5)
  const int cl = lane & 31, lh = lane >> 5;
  if (rb < 6) {
#pragma unroll
    for (int mi = 0; mi < 2; ++mi)
#pragma unroll
      for (int ni = 0; ni < 2; ++ni) {
        const int p = col0 + wn * 64 + ni * 32 + cl;
#pragma unroll
        for (int r = 0; r < 16; ++r) {
          const int row = (r & 3) + 8 * (r >> 2) + 4 * lh;
          const int m = row0 + wm * 64 + mi * 32 + row;
          qkvraw[((size_t)s * D3_ + m) * HW_ + p] = acc[mi][ni][r];
        }
      }
  } else {
#pragma unroll
    for (int mi = 0; mi < 2; ++mi)
#pragma unroll
      for (int ni = 0; ni < 2; ++ni) {
        const int p = col0 + wn * 64 + ni * 32 + cl;
#pragma unroll
        for (int r = 0; r < 16; ++r) {
          const int row = (r & 3) + 8 * (r >> 2) + 4 * lh;
          const int gr = wm * 64 + mi * 32 + row;  // 0..127
          g1[((size_t)s * 128 + gr) * HW_ + p] = fmaxf(acc[mi][ni][r] + gb1[gr], 0.f);
        }
      }
  }
}

// ---------------------------------------------------------------------------
// K2: gate second layer: per-pixel sigmoid(w2 . g1 + b2), block-sum partials.
// ---------------------------------------------------------------------------
__global__ __launch_bounds__(256) void k2_gate(
    const float* __restrict__ g1, const float* __restrict__ w2,
    const float* __restrict__ b2, float* __restrict__ gpart, int bbase)
{
  const int t = threadIdx.x;
  const int blk = blockIdx.x;
  const int s = blockIdx.y;
  const int b = bbase + s;
  const int p = blk * 256 + t;
  const float* gp = g1 + (size_t)s * 128 * HW_ + p;
  float sv = b2[0];
#pragma unroll 8
  for (int c = 0; c < 128; ++c) sv += gp[(size_t)c * HW_] * w2[c];
  const float sig = 1.f / (1.f + expf(-sv));
  __shared__ float red[256];
  red[t] = sig;
  __syncthreads();
  for (int o = 128; o > 0; o >>= 1) {
    if (t < o) red[t] += red[t + o];
    __syncthreads();
  }
  if (t == 0) gpart[b * 64 + blk] = red[0];
}

// ---------------------------------------------------------------------------
// K3a: depthwise 3x3 (SAME zero pad). q,k -> qdw/kdw (+ ssq partials); v -> out.
// ---------------------------------------------------------------------------
__global__ __launch_bounds__(256) void k3a_dw(
    const float* __restrict__ qkvraw, const float* __restrict__ wdw,
    float* __restrict__ uni, float* __restrict__ vout,
    float* __restrict__ ssq_part, int bbase)
{
  const int t = threadIdx.x;
  const int ytile = blockIdx.x;
  const int ch = blockIdx.y;
  const int s = blockIdx.z;
  const int b = bbase + s;
  const int y0 = ytile * 8;
  float* qdw = uni + (size_t)s * 512 * HW_;
  float* kdw = qdw + (size_t)DIM_ * HW_;

  __shared__ float sm[10][130];
  const float* in = qkvraw + ((size_t)s * D3_ + ch) * HW_;
  for (int i = t; i < 1300; i += 256) {
    const int r = i / 130;
    const int xx = i - r * 130 - 1;
    const int row = y0 - 1 + r;
    float v = 0.f;
    if (row >= 0 && row < IMG_H && xx >= 0 && xx < IMG_W)
      v = in[row * IMG_W + xx];
    sm[r][i - r * 130] = v;
  }
  const float* wp = wdw + ch * 9;
  const float w00 = wp[0], w01 = wp[1], w02 = wp[2],
              w10 = wp[3], w11 = wp[4], w12 = wp[5],
              w20 = wp[6], w21 = wp[7], w22 = wp[8];
  __syncthreads();

  float* outp;
  if (ch < 256)       outp = qdw + (size_t)ch * HW_;
  else if (ch < 512)  outp = kdw + (size_t)(ch - 256) * HW_;
  else                outp = vout + ((size_t)b * DIM_ + (ch - 512)) * HW_;

  float sq = 0.f;
#pragma unroll
  for (int it = 0; it < 4; ++it) {
    const int px = t + it * 256;
    const int yl = px >> 7, xx = px & 127;
    const float a =
      w00 * sm[yl][xx]     + w01 * sm[yl][xx + 1]     + w02 * sm[yl][xx + 2] +
      w10 * sm[yl + 1][xx] + w11 * sm[yl + 1][xx + 1] + w12 * sm[yl + 1][xx + 2] +
      w20 * sm[yl + 2][xx] + w21 * sm[yl + 2][xx + 1] + w22 * sm[yl + 2][xx + 2];
    outp[y0 * IMG_W + px] = a;
    sq += a * a;
  }

  if (ch < 512) {
    __shared__ float red[256];
    red[t] = sq;
    __syncthreads();
    for (int o = 128; o > 0; o >>= 1) {
      if (t < o) red[t] += red[t + o];
      __syncthreads();
    }
    if (t == 0) ssq_part[((size_t)b * 512 + ch) * 16 + ytile] = red[0];
  }
}

// ---------------------------------------------------------------------------
// K3b: Gram partials over 512-pixel chunks (32 chunks per b,h).
// ---------------------------------------------------------------------------
__global__ __launch_bounds__(256) void k3b_gram(
    const float* __restrict__ uni, float* __restrict__ S_part, int bbase)
{
  const int t = threadIdx.x;
  const int chunk = blockIdx.x;  // 0..31
  const int h = blockIdx.y;
  const int s = blockIdx.z;
  const int b = bbase + s;
  const int p0 = chunk * 512;
  const float* qdw = uni + (size_t)s * 512 * HW_;
  const float* kdw = qdw + (size_t)DIM_ * HW_;

  __shared__ float qs[64][68];
  __shared__ float ks[64][68];

  const int rc = t >> 4, dc = t & 15;

  float acc[4][4];
#pragma unroll
  for (int i = 0; i < 4; ++i)
#pragma unroll
    for (int j = 0; j < 4; ++j) acc[i][j] = 0.f;

  const float* qbase = qdw + (size_t)h * 64 * HW_ + p0;
  const float* kbase = kdw + (size_t)h * 64 * HW_ + p0;

  for (int kk = 0; kk < 512; kk += 64) {
    __syncthreads();
#pragma unroll
    for (int j = 0; j < 4; ++j) {
      const int lin = t + j * 256;
      const int c = lin >> 4;
      const int px0 = (lin & 15) << 2;
      const float4 qv = *(const float4*)(qbase + (size_t)c * HW_ + kk + px0);
      const float4 kv = *(const float4*)(kbase + (size_t)c * HW_ + kk + px0);
      qs[px0 + 0][c] = qv.x; qs[px0 + 1][c] = qv.y;
      qs[px0 + 2][c] = qv.z; qs[px0 + 3][c] = qv.w;
      ks[px0 + 0][c] = kv.x; ks[px0 + 1][c] = kv.y;
      ks[px0 + 2][c] = kv.z; ks[px0 + 3][c] = kv.w;
    }
    __syncthreads();
#pragma unroll 4
    for (int p = 0; p < 64; ++p) {
      const float4 q4 = *(const float4*)&qs[p][rc * 4];
      const float4 k4 = *(const float4*)&ks[p][dc * 4];
      const float qa[4] = {q4.x, q4.y, q4.z, q4.w};
      const float ka[4] = {k4.x, k4.y, k4.z, k4.w};
#pragma unroll
      for (int i = 0; i < 4; ++i)
#pragma unroll
        for (int jj = 0; jj < 4; ++jj) acc[i][jj] += qa[i] * ka[jj];
    }
  }
  float* op = S_part + (((size_t)(b * HEADS_ + h)) * 32 + chunk) * 4096;
#pragma unroll
  for (int i = 0; i < 4; ++i) {
    float4 v;
    v.x = acc[i][0]; v.y = acc[i][1]; v.z = acc[i][2]; v.w = acc[i][3];
    *(float4*)(op + (rc * 4 + i) * 64 + dc * 4) = v;
  }
}

// ---------------------------------------------------------------------------
// K3c: parallel reduce S_part[32 chunks] -> S. Fully coalesced.
// ---------------------------------------------------------------------------
__global__ __launch_bounds__(256) void k3c_reduce(
    const float* __restrict__ S_part, float* __restrict__ S)
{
  const int t = threadIdx.x;
  const int bh = blockIdx.y;
  const int e = blockIdx.x * 256 + t;
  float sum = 0.f;
#pragma unroll 8
  for (int c = 0; c < 32; ++c)
    sum += S_part[((size_t)bh * 32 + c) * 4096 + e];
  S[(size_t)bh * 4096 + e] = sum;
}

// ---------------------------------------------------------------------------
// K4: finalize attention. 256 threads (4 waves) per (b,h); each wave does 16
// rows: norm-scale, rank-based top-k mask, masked softmax, fold a1..a4 scale.
// ---------------------------------------------------------------------------
__global__ __launch_bounds__(256) void k4_final(
    const float* __restrict__ S, const float* __restrict__ ssq_part,
    const float* __restrict__ gpart, const float* __restrict__ temperature,
    const float* __restrict__ a1, const float* __restrict__ a2,
    const float* __restrict__ a3, const float* __restrict__ a4,
    float* __restrict__ attn)
{
  const int t = threadIdx.x;
  const int lane = t & 63, w = t >> 6;
  const int bh = blockIdx.x;
  const int b = bh >> 2, h = bh & 3;

  __shared__ float red[256];
  __shared__ float invq[64], invk[64];

  red[t] = gpart[t] + gpart[t + 256];
  __syncthreads();
  for (int o = 128; o > 0; o >>= 1) {
    if (t < o) red[t] += red[t + o];
    __syncthreads();
  }
  const float mean = red[0] / (float)((size_t)B_ * HW_);
  int dk = (int)floorf((float)C_ * mean);
  dk = min(max(dk, 1), 64);

  if (t < 128) {
    const int d = t & 63;
    const int ch = (t < 64 ? 0 : 256) + h * 64 + d;
    const float* pp = ssq_part + ((size_t)b * 512 + ch) * 16;
    float sv = 0.f;
#pragma unroll
    for (int yt = 0; yt < 16; ++yt) sv += pp[yt];
    const float inv = 1.f / fmaxf(sqrtf(sv), 1e-12f);
    if (t < 64) invq[d] = inv; else invk[d] = inv;
  }
  __syncthreads();

  const float tval = temperature[h];
  const float ascale = a1[0] + a2[0] + a3[0] + a4[0];
  const float* Sp = S + (size_t)bh * 4096;
  float* op = attn + (size_t)bh * 4096;

  for (int i = 0; i < 16; ++i) {
    const int c = w * 16 + i;
    const float val = Sp[c * 64 + lane] * invq[c] * invk[lane] * tval;
    int rank = 0;
    for (int j = 0; j < 64; ++j) {
      const float vj = __shfl(val, j, 64);
      rank += ((vj > val) || (vj == val && j < lane)) ? 1 : 0;
    }
    const bool keep = rank < dk;
    float mv = keep ? val : -INFINITY;
#pragma unroll
    for (int m = 1; m < 64; m <<= 1) mv = fmaxf(mv, __shfl_xor(mv, m, 64));
    const float e = keep ? expf(val - mv) : 0.f;
    float ssum = e;
#pragma unroll
    for (int m = 1; m < 64; m <<= 1) ssum += __shfl_xor(ssum, m, 64);
    op[c * 64 + lane] = (e / ssum) * ascale;
  }
}

// ---------------------------------------------------------------------------
// K5: out = attn @ v, in place on d_out (v lives there; scale folded in attn).
// ---------------------------------------------------------------------------
__global__ __launch_bounds__(256) void k5_av(
    const float* __restrict__ attn, float* __restrict__ out)
{
  const int t = threadIdx.x;
  const int pc = blockIdx.x;
  const int h = blockIdx.y;
  const int b = blockIdx.z;
  const int p0 = pc * 512;

  __shared__ float As5[4096];
  const float* ap = attn + ((size_t)(b * HEADS_ + h)) * 4096;
#pragma unroll
  for (int j = 0; j < 4; ++j) {
    const int idx = (t + j * 256) * 4;
    *(float4*)&As5[idx] = *(const float4*)(ap + idx);
  }
  float* base = out + ((size_t)b * DIM_ + h * 64) * HW_ + p0;

  float v0[64], v1[64];
#pragma unroll
  for (int dd = 0; dd < 64; ++dd) {
    v0[dd] = base[(size_t)dd * HW_ + t];
    v1[dd] = base[(size_t)dd * HW_ + t + 256];
  }
  __syncthreads();

  for (int c = 0; c < 64; ++c) {
    float acc0 = 0.f, acc1 = 0.f;
#pragma unroll
    for (int d4 = 0; d4 < 16; ++d4) {
      const float4 a = *(const float4*)&As5[c * 64 + d4 * 4];
      acc0 = fmaf(a.x, v0[d4 * 4 + 0], acc0);
      acc0 = fmaf(a.y, v0[d4 * 4 + 1], acc0);
      acc0 = fmaf(a.z, v0[d4 * 4 + 2], acc0);
      acc0 = fmaf(a.w, v0[d4 * 4 + 3], acc0);
      acc1 = fmaf(a.x, v1[d4 * 4 + 0], acc1);
      acc1 = fmaf(a.y, v1[d4 * 4 + 1], acc1);
      acc1 = fmaf(a.z, v1[d4 * 4 + 2], acc1);
      acc1 = fmaf(a.w, v1[d4 * 4 + 3], acc1);
    }
    base[(size_t)c * HW_ + t] = acc0;
    base[(size_t)c * HW_ + t + 256] = acc1;
  }
}

// ---------------------------------------------------------------------------
extern "C" void kernel_launch(void* const* d_in, const int* in_sizes, int n_in,
                              void* d_out, int out_size, void* d_ws, size_t ws_size,
                              hipStream_t stream)
{
  const float* x    = (const float*)d_in[0];
  const float* wqkv = (const float*)d_in[1];
  const float* wdw  = (const float*)d_in[2];
  const float* temp = (const float*)d_in[3];
  const float* a1   = (const float*)d_in[4];
  const float* a2   = (const float*)d_in[5];
  const float* a3   = (const float*)d_in[6];
  const float* a4   = (const float*)d_in[7];
  const float* gw1  = (const float*)d_in[8];
  const float* gb1  = (const float*)d_in[9];
  const float* gw2  = (const float*)d_in[10];
  const float* gb2  = (const float*)d_in[11];
  float* out = (float*)d_out;
  (void)in_sizes; (void)n_in; (void)out_size;

  const size_t HWs = (size_t)HW_;
  // per-slot: qkvraw (768) + g1 (128) + union[Xt bf16 | qdw,kdw fp32] (512)
  const size_t perb_f = (size_t)1408 * HWs;
  const size_t fixed_f = (size_t)32 * 32 * 4096   // S_part
                       + (size_t)32 * 4096        // S
                       + (size_t)8 * 512 * 16     // ssq partials
                       + 512                      // gate partials
                       + (size_t)32 * 4096        // attn
                       + (size_t)2 * 896 * 256 / 2 + 64;  // WH+WL (ushort) as floats
  int NB = 8;
  while (NB > 1) {
    if ((perb_f * (size_t)NB + fixed_f) * 4 <= ws_size) break;
    NB >>= 1;
  }

  float* ws = (float*)d_ws;
  size_t off = 0;
  float* qkvraw = ws + off; off += (size_t)NB * D3_ * HWs;
  float* g1     = ws + off; off += (size_t)NB * 128 * HWs;
  float* uni    = ws + off; off += (size_t)NB * 512 * HWs;
  float* S_part = ws + off; off += (size_t)32 * 32 * 4096;
  float* S      = ws + off; off += (size_t)32 * 4096;
  float* ssqp   = ws + off; off += (size_t)8 * 512 * 16;
  float* gpart  = ws + off; off += 512;
  float* attnb  = ws + off; off += (size_t)32 * 4096;
  ushort_t* WH  = (ushort_t*)(ws + off);
  ushort_t* WL  = WH + (size_t)896 * 256;

  k0_wsplit<<<dim3(896), 256, 0, stream>>>(wqkv, gw1, WH, WL);

  for (int g = 0; g < B_ / NB; ++g) {
    const int bbase = g * NB;
    k0_xt<<<dim3(512, 8, NB), 256, 0, stream>>>(x, uni, bbase);
    k1_mfma<<<dim3(128, 7, NB), 256, 0, stream>>>(WH, WL, uni, gb1, qkvraw, g1);
    k2_gate<<<dim3(64, NB, 1), 256, 0, stream>>>(g1, gw2, gb2, gpart, bbase);
    k3a_dw<<<dim3(16, 768, NB), 256, 0, stream>>>(qkvraw, wdw, uni, out, ssqp, bbase);
    k3b_gram<<<dim3(32, 4, NB), 256, 0, stream>>>(uni, S_part, bbase);
  }
  k3c_reduce<<<dim3(16, 32), 256, 0, stream>>>(S_part, S);
  k4_final<<<dim3(32), 256, 0, stream>>>(S, ssqp, gpart, temp, a1, a2, a3, a4, attnb);
  k5_av<<<dim3(32, 4, 8), 256, 0, stream>>>(attnb, out);
}

// Round 3
// 848.774 us; speedup vs baseline: 1.8576x; 1.0883x over previous
//
#include <hip/hip_runtime.h>
#include <hip/hip_bf16.h>
#include <cmath>

#define HW_ 16384
#define IMG_W 128
#define IMG_H 128
#define DIM_ 256
#define D3_ 768
#define HEADS_ 4
#define C_ 64
#define B_ 8

typedef unsigned short ushort_t;
typedef __attribute__((ext_vector_type(8))) short short8v;
typedef __attribute__((ext_vector_type(16))) float f32x16;

#define GLL16(gp, lp) __builtin_amdgcn_global_load_lds( \
    (const __attribute__((address_space(1))) void*)(gp), \
    (__attribute__((address_space(3))) void*)(lp), 16, 0, 0)

static __device__ __forceinline__ ushort_t f2bf_bits(float v) {
  __hip_bfloat16 h = __float2bfloat16(v);
  return *reinterpret_cast<ushort_t*>(&h);
}

// ---------------------------------------------------------------------------
// K0a: split W (w_qkv rows 0..767, gw1 rows 768..895) into bf16 hi/lo.
// ---------------------------------------------------------------------------
__global__ __launch_bounds__(256) void k0_wsplit(
    const float* __restrict__ wqkv, const float* __restrict__ gw1,
    ushort_t* __restrict__ WH, ushort_t* __restrict__ WL)
{
  const int row = blockIdx.x;
  const int t = threadIdx.x;
  const float* src = (row < 768) ? (wqkv + (size_t)row * DIM_)
                                 : (gw1 + (size_t)(row - 768) * DIM_);
  const float v = src[t];
  const ushort_t hb = f2bf_bits(v);
  __hip_bfloat16 h = *reinterpret_cast<const __hip_bfloat16*>(&hb);
  const float hf = __bfloat162float(h);
  WH[(size_t)row * DIM_ + t] = hb;
  WL[(size_t)row * DIM_ + t] = f2bf_bits(v - hf);
}

// ---------------------------------------------------------------------------
// K0b: transpose+split X[b] [256][16384] -> XtH/XtL [16384][256] bf16.
// ---------------------------------------------------------------------------
__global__ __launch_bounds__(256) void k0_xt(
    const float* __restrict__ x, float* __restrict__ uni, int bbase)
{
  const int t = threadIdx.x;
  const int s = blockIdx.z;
  const int b = bbase + s;
  ushort_t* XtH = (ushort_t*)(uni + (size_t)s * 512 * HW_);
  ushort_t* XtL = XtH + (size_t)DIM_ * HW_;
  const int p0 = blockIdx.x * 32, c0 = blockIdx.y * 32;
  const int tx = t & 31, ty = t >> 5;

  __shared__ float sm[32][33];
#pragma unroll
  for (int i = 0; i < 4; ++i) {
    const int c = c0 + ty + i * 8;
    sm[ty + i * 8][tx] = x[((size_t)b * DIM_ + c) * HW_ + p0 + tx];
  }
  __syncthreads();
#pragma unroll
  for (int i = 0; i < 4; ++i) {
    const int p = p0 + ty + i * 8;
    const float v = sm[tx][ty + i * 8];
    const ushort_t hb = f2bf_bits(v);
    __hip_bfloat16 h = *reinterpret_cast<const __hip_bfloat16*>(&hb);
    const float hf = __bfloat162float(h);
    XtH[(size_t)p * DIM_ + c0 + tx] = hb;
    XtL[(size_t)p * DIM_ + c0 + tx] = f2bf_bits(v - hf);
  }
}

// ---------------------------------------------------------------------------
// K1: MFMA GEMM (bf16 hi/lo split, 3 MFMA per product). C[896][16384] per b.
// Staging via global_load_lds width=16 (LDS layout is wave-contiguous:
// bytes i*4096 + wave*1024 + lane*16).
// ---------------------------------------------------------------------------
__global__ __launch_bounds__(256, 2) void k1_mfma(
    const ushort_t* __restrict__ WH, const ushort_t* __restrict__ WL,
    const float* __restrict__ uni, const float* __restrict__ gb1,
    float* __restrict__ qkvraw, float* __restrict__ g1)
{
  const int t = threadIdx.x;
  const int cb = blockIdx.x, rb = blockIdx.y, s = blockIdx.z;
  const int row0 = rb * 128, col0 = cb * 128;
  const ushort_t* XtH = (const ushort_t*)(uni + (size_t)s * 512 * HW_);
  const ushort_t* XtL = XtH + (size_t)DIM_ * HW_;

  __shared__ __align__(16) ushort_t lds[4 * 8192];  // 64 KB
  ushort_t* AH = lds;
  ushort_t* AL = lds + 8192;
  ushort_t* BH = lds + 16384;
  ushort_t* BL = lds + 24576;

  const int lane = t & 63, wid = t >> 6;
  const int wm = wid >> 1, wn = wid & 1;
  const int rr = t & 31, w8 = t >> 5;

  f32x16 acc[2][2];
#pragma unroll
  for (int mi = 0; mi < 2; ++mi)
#pragma unroll
    for (int ni = 0; ni < 2; ++ni)
#pragma unroll
      for (int r = 0; r < 16; ++r) acc[mi][ni][r] = 0.f;

  for (int kt = 0; kt < 4; ++kt) {
    const int k0 = kt * 64;
    __syncthreads();
    {
      const int koff = k0 + w8 * 8;   // per-lane k offset
#pragma unroll
      for (int i = 0; i < 4; ++i) {
        const size_t arow = (size_t)(row0 + i * 32 + rr);
        const size_t prow = (size_t)(col0 + i * 32 + rr);
        const int lo_s = i * 2048 + wid * 512;  // shorts; wave-uniform
        GLL16(WH + arow * DIM_ + koff, AH + lo_s);
        GLL16(WL + arow * DIM_ + koff, AL + lo_s);
        GLL16(XtH + prow * DIM_ + koff, BH + lo_s);
        GLL16(XtL + prow * DIM_ + koff, BL + lo_s);
      }
    }
    __syncthreads();
    const int lo = lane * 8;
#pragma unroll
    for (int ks = 0; ks < 4; ++ks) {
      short8v ah[2], al[2], bh[2], bl[2];
#pragma unroll
      for (int mi = 0; mi < 2; ++mi) {
        const int base = ((wm * 2 + mi) * 8 + ks * 2) * 256 + lo;
        ah[mi] = *(const short8v*)(AH + base);
        al[mi] = *(const short8v*)(AL + base);
      }
#pragma unroll
      for (int ni = 0; ni < 2; ++ni) {
        const int base = ((wn * 2 + ni) * 8 + ks * 2) * 256 + lo;
        bh[ni] = *(const short8v*)(BH + base);
        bl[ni] = *(const short8v*)(BL + base);
      }
#pragma unroll
      for (int mi = 0; mi < 2; ++mi)
#pragma unroll
        for (int ni = 0; ni < 2; ++ni) {
          acc[mi][ni] = __builtin_amdgcn_mfma_f32_32x32x16_bf16(
              ah[mi], bh[ni], acc[mi][ni], 0, 0, 0);
          acc[mi][ni] = __builtin_amdgcn_mfma_f32_32x32x16_bf16(
              ah[mi], bl[ni], acc[mi][ni], 0, 0, 0);
          acc[mi][ni] = __builtin_amdgcn_mfma_f32_32x32x16_bf16(
              al[mi], bh[ni], acc[mi][ni], 0, 0, 0);
        }
    }
  }

  // Epilogue: C/D layout col=lane&31, row=(reg&3)+8*(reg>>2)+4*(lane>>5)
  const int cl = lane & 31, lh = lane >> 5;
  if (rb < 6) {
#pragma unroll
    for (int mi = 0; mi < 2; ++mi)
#pragma unroll
      for (int ni = 0; ni < 2; ++ni) {
        const int p = col0 + wn * 64 + ni * 32 + cl;
#pragma unroll
        for (int r = 0; r < 16; ++r) {
          const int row = (r & 3) + 8 * (r >> 2) + 4 * lh;
          const int m = row0 + wm * 64 + mi * 32 + row;
          qkvraw[((size_t)s * D3_ + m) * HW_ + p] = acc[mi][ni][r];
        }
      }
  } else {
#pragma unroll
    for (int mi = 0; mi < 2; ++mi)
#pragma unroll
      for (int ni = 0; ni < 2; ++ni) {
        const int p = col0 + wn * 64 + ni * 32 + cl;
#pragma unroll
        for (int r = 0; r < 16; ++r) {
          const int row = (r & 3) + 8 * (r >> 2) + 4 * lh;
          const int gr = wm * 64 + mi * 32 + row;  // 0..127
          g1[((size_t)s * 128 + gr) * HW_ + p] = fmaxf(acc[mi][ni][r] + gb1[gr], 0.f);
        }
      }
  }
}

// ---------------------------------------------------------------------------
// K2: gate second layer: per-pixel sigmoid(w2 . g1 + b2), block-sum partials.
// ---------------------------------------------------------------------------
__global__ __launch_bounds__(256) void k2_gate(
    const float* __restrict__ g1, const float* __restrict__ w2,
    const float* __restrict__ b2, float* __restrict__ gpart, int bbase)
{
  const int t = threadIdx.x;
  const int blk = blockIdx.x;
  const int s = blockIdx.y;
  const int b = bbase + s;
  const int p = blk * 256 + t;
  const float* gp = g1 + (size_t)s * 128 * HW_ + p;
  float sv = b2[0];
#pragma unroll 8
  for (int c = 0; c < 128; ++c) sv += gp[(size_t)c * HW_] * w2[c];
  const float sig = 1.f / (1.f + expf(-sv));
  __shared__ float red[256];
  red[t] = sig;
  __syncthreads();
  for (int o = 128; o > 0; o >>= 1) {
    if (t < o) red[t] += red[t + o];
    __syncthreads();
  }
  if (t == 0) gpart[b * 64 + blk] = red[0];
}

// ---------------------------------------------------------------------------
// K3a: depthwise 3x3 (SAME zero pad). q,k -> qdw/kdw (+ ssq partials); v -> out.
// ---------------------------------------------------------------------------
__global__ __launch_bounds__(256) void k3a_dw(
    const float* __restrict__ qkvraw, const float* __restrict__ wdw,
    float* __restrict__ uni, float* __restrict__ vout,
    float* __restrict__ ssq_part, int bbase)
{
  const int t = threadIdx.x;
  const int ytile = blockIdx.x;
  const int ch = blockIdx.y;
  const int s = blockIdx.z;
  const int b = bbase + s;
  const int y0 = ytile * 8;
  float* qdw = uni + (size_t)s * 512 * HW_;
  float* kdw = qdw + (size_t)DIM_ * HW_;

  __shared__ float sm[10][130];
  const float* in = qkvraw + ((size_t)s * D3_ + ch) * HW_;
  for (int i = t; i < 1300; i += 256) {
    const int r = i / 130;
    const int xx = i - r * 130 - 1;
    const int row = y0 - 1 + r;
    float v = 0.f;
    if (row >= 0 && row < IMG_H && xx >= 0 && xx < IMG_W)
      v = in[row * IMG_W + xx];
    sm[r][i - r * 130] = v;
  }
  const float* wp = wdw + ch * 9;
  const float w00 = wp[0], w01 = wp[1], w02 = wp[2],
              w10 = wp[3], w11 = wp[4], w12 = wp[5],
              w20 = wp[6], w21 = wp[7], w22 = wp[8];
  __syncthreads();

  float* outp;
  if (ch < 256)       outp = qdw + (size_t)ch * HW_;
  else if (ch < 512)  outp = kdw + (size_t)(ch - 256) * HW_;
  else                outp = vout + ((size_t)b * DIM_ + (ch - 512)) * HW_;

  float sq = 0.f;
#pragma unroll
  for (int it = 0; it < 4; ++it) {
    const int px = t + it * 256;
    const int yl = px >> 7, xx = px & 127;
    const float a =
      w00 * sm[yl][xx]     + w01 * sm[yl][xx + 1]     + w02 * sm[yl][xx + 2] +
      w10 * sm[yl + 1][xx] + w11 * sm[yl + 1][xx + 1] + w12 * sm[yl + 1][xx + 2] +
      w20 * sm[yl + 2][xx] + w21 * sm[yl + 2][xx + 1] + w22 * sm[yl + 2][xx + 2];
    outp[y0 * IMG_W + px] = a;
    sq += a * a;
  }

  if (ch < 512) {
    __shared__ float red[256];
    red[t] = sq;
    __syncthreads();
    for (int o = 128; o > 0; o >>= 1) {
      if (t < o) red[t] += red[t + o];
      __syncthreads();
    }
    if (t == 0) ssq_part[((size_t)b * 512 + ch) * 16 + ytile] = red[0];
  }
}

// ---------------------------------------------------------------------------
// K3b: Gram partials over 512-pixel chunks (32 chunks per b,h).
// ---------------------------------------------------------------------------
__global__ __launch_bounds__(256) void k3b_gram(
    const float* __restrict__ uni, float* __restrict__ S_part, int bbase)
{
  const int t = threadIdx.x;
  const int chunk = blockIdx.x;  // 0..31
  const int h = blockIdx.y;
  const int s = blockIdx.z;
  const int b = bbase + s;
  const int p0 = chunk * 512;
  const float* qdw = uni + (size_t)s * 512 * HW_;
  const float* kdw = qdw + (size_t)DIM_ * HW_;

  __shared__ float qs[64][68];
  __shared__ float ks[64][68];

  const int rc = t >> 4, dc = t & 15;

  float acc[4][4];
#pragma unroll
  for (int i = 0; i < 4; ++i)
#pragma unroll
    for (int j = 0; j < 4; ++j) acc[i][j] = 0.f;

  const float* qbase = qdw + (size_t)h * 64 * HW_ + p0;
  const float* kbase = kdw + (size_t)h * 64 * HW_ + p0;

  for (int kk = 0; kk < 512; kk += 64) {
    __syncthreads();
#pragma unroll
    for (int j = 0; j < 4; ++j) {
      const int lin = t + j * 256;
      const int c = lin >> 4;
      const int px0 = (lin & 15) << 2;
      const float4 qv = *(const float4*)(qbase + (size_t)c * HW_ + kk + px0);
      const float4 kv = *(const float4*)(kbase + (size_t)c * HW_ + kk + px0);
      qs[px0 + 0][c] = qv.x; qs[px0 + 1][c] = qv.y;
      qs[px0 + 2][c] = qv.z; qs[px0 + 3][c] = qv.w;
      ks[px0 + 0][c] = kv.x; ks[px0 + 1][c] = kv.y;
      ks[px0 + 2][c] = kv.z; ks[px0 + 3][c] = kv.w;
    }
    __syncthreads();
#pragma unroll 4
    for (int p = 0; p < 64; ++p) {
      const float4 q4 = *(const float4*)&qs[p][rc * 4];
      const float4 k4 = *(const float4*)&ks[p][dc * 4];
      const float qa[4] = {q4.x, q4.y, q4.z, q4.w};
      const float ka[4] = {k4.x, k4.y, k4.z, k4.w};
#pragma unroll
      for (int i = 0; i < 4; ++i)
#pragma unroll
        for (int jj = 0; jj < 4; ++jj) acc[i][jj] += qa[i] * ka[jj];
    }
  }
  float* op = S_part + (((size_t)(b * HEADS_ + h)) * 32 + chunk) * 4096;
#pragma unroll
  for (int i = 0; i < 4; ++i) {
    float4 v;
    v.x = acc[i][0]; v.y = acc[i][1]; v.z = acc[i][2]; v.w = acc[i][3];
    *(float4*)(op + (rc * 4 + i) * 64 + dc * 4) = v;
  }
}

// ---------------------------------------------------------------------------
// K3c: parallel reduce S_part[32 chunks] -> S. Fully coalesced.
// ---------------------------------------------------------------------------
__global__ __launch_bounds__(256) void k3c_reduce(
    const float* __restrict__ S_part, float* __restrict__ S)
{
  const int t = threadIdx.x;
  const int bh = blockIdx.y;
  const int e = blockIdx.x * 256 + t;
  float sum = 0.f;
#pragma unroll 8
  for (int c = 0; c < 32; ++c)
    sum += S_part[((size_t)bh * 32 + c) * 4096 + e];
  S[(size_t)bh * 4096 + e] = sum;
}

// ---------------------------------------------------------------------------
// K4: finalize attention. 256 threads (4 waves) per (b,h).
// ---------------------------------------------------------------------------
__global__ __launch_bounds__(256) void k4_final(
    const float* __restrict__ S, const float* __restrict__ ssq_part,
    const float* __restrict__ gpart, const float* __restrict__ temperature,
    const float* __restrict__ a1, const float* __restrict__ a2,
    const float* __restrict__ a3, const float* __restrict__ a4,
    float* __restrict__ attn)
{
  const int t = threadIdx.x;
  const int lane = t & 63, w = t >> 6;
  const int bh = blockIdx.x;
  const int b = bh >> 2, h = bh & 3;

  __shared__ float red[256];
  __shared__ float invq[64], invk[64];

  red[t] = gpart[t] + gpart[t + 256];
  __syncthreads();
  for (int o = 128; o > 0; o >>= 1) {
    if (t < o) red[t] += red[t + o];
    __syncthreads();
  }
  const float mean = red[0] / (float)((size_t)B_ * HW_);
  int dk = (int)floorf((float)C_ * mean);
  dk = min(max(dk, 1), 64);

  if (t < 128) {
    const int d = t & 63;
    const int ch = (t < 64 ? 0 : 256) + h * 64 + d;
    const float* pp = ssq_part + ((size_t)b * 512 + ch) * 16;
    float sv = 0.f;
#pragma unroll
    for (int yt = 0; yt < 16; ++yt) sv += pp[yt];
    const float inv = 1.f / fmaxf(sqrtf(sv), 1e-12f);
    if (t < 64) invq[d] = inv; else invk[d] = inv;
  }
  __syncthreads();

  const float tval = temperature[h];
  const float ascale = a1[0] + a2[0] + a3[0] + a4[0];
  const float* Sp = S + (size_t)bh * 4096;
  float* op = attn + (size_t)bh * 4096;

  for (int i = 0; i < 16; ++i) {
    const int c = w * 16 + i;
    const float val = Sp[c * 64 + lane] * invq[c] * invk[lane] * tval;
    int rank = 0;
    for (int j = 0; j < 64; ++j) {
      const float vj = __shfl(val, j, 64);
      rank += ((vj > val) || (vj == val && j < lane)) ? 1 : 0;
    }
    const bool keep = rank < dk;
    float mv = keep ? val : -INFINITY;
#pragma unroll
    for (int m = 1; m < 64; m <<= 1) mv = fmaxf(mv, __shfl_xor(mv, m, 64));
    const float e = keep ? expf(val - mv) : 0.f;
    float ssum = e;
#pragma unroll
    for (int m = 1; m < 64; m <<= 1) ssum += __shfl_xor(ssum, m, 64);
    op[c * 64 + lane] = (e / ssum) * ascale;
  }
}

// ---------------------------------------------------------------------------
// K5: out = attn @ v in place on d_out. LDS-staged v tile [64][128] (32KB) +
// attn (16KB). Thread = 8 channels x 4 pixels, acc in 8 float4s.
// ---------------------------------------------------------------------------
__global__ __launch_bounds__(256) void k5_av(
    const float* __restrict__ attn, float* __restrict__ out)
{
  const int t = threadIdx.x;
  const int pc = blockIdx.x;  // 0..127
  const int h = blockIdx.y;
  const int b = blockIdx.z;
  const int p0 = pc * 128;

  __shared__ float vs[64][128];   // 32 KB
  __shared__ float As5[64][64];   // 16 KB

  const float* ap = attn + ((size_t)(b * HEADS_ + h)) * 4096;
  float* As5f = &As5[0][0];
#pragma unroll
  for (int j = 0; j < 4; ++j) {
    const int idx = t * 4 + j * 1024;
    *(float4*)&As5f[idx] = *(const float4*)(ap + idx);
  }

  float* base = out + ((size_t)b * DIM_ + h * 64) * HW_ + p0;
#pragma unroll
  for (int k = 0; k < 8; ++k) {
    const int fi = (t + k * 256) * 4;
    const int r = fi >> 7, c = fi & 127;
    *(float4*)&vs[r][c] = *(const float4*)(base + (size_t)r * HW_ + c);
  }
  __syncthreads();

  const int px4 = (t & 31) * 4;
  const int ch0 = (t >> 5) * 8;

  float4 acc[8];
#pragma unroll
  for (int ci = 0; ci < 8; ++ci) acc[ci] = make_float4(0.f, 0.f, 0.f, 0.f);

#pragma unroll 4
  for (int d = 0; d < 64; ++d) {
    const float4 v4 = *(const float4*)&vs[d][px4];
#pragma unroll
    for (int ci = 0; ci < 8; ++ci) {
      const float a = As5[ch0 + ci][d];
      acc[ci].x = fmaf(a, v4.x, acc[ci].x);
      acc[ci].y = fmaf(a, v4.y, acc[ci].y);
      acc[ci].z = fmaf(a, v4.z, acc[ci].z);
      acc[ci].w = fmaf(a, v4.w, acc[ci].w);
    }
  }

#pragma unroll
  for (int ci = 0; ci < 8; ++ci)
    *(float4*)(base + (size_t)(ch0 + ci) * HW_ + px4) = acc[ci];
}

// ---------------------------------------------------------------------------
extern "C" void kernel_launch(void* const* d_in, const int* in_sizes, int n_in,
                              void* d_out, int out_size, void* d_ws, size_t ws_size,
                              hipStream_t stream)
{
  const float* x    = (const float*)d_in[0];
  const float* wqkv = (const float*)d_in[1];
  const float* wdw  = (const float*)d_in[2];
  const float* temp = (const float*)d_in[3];
  const float* a1   = (const float*)d_in[4];
  const float* a2   = (const float*)d_in[5];
  const float* a3   = (const float*)d_in[6];
  const float* a4   = (const float*)d_in[7];
  const float* gw1  = (const float*)d_in[8];
  const float* gb1  = (const float*)d_in[9];
  const float* gw2  = (const float*)d_in[10];
  const float* gb2  = (const float*)d_in[11];
  float* out = (float*)d_out;
  (void)in_sizes; (void)n_in; (void)out_size;

  const size_t HWs = (size_t)HW_;
  const size_t perb_f = (size_t)1408 * HWs;
  const size_t fixed_f = (size_t)32 * 32 * 4096
                       + (size_t)32 * 4096
                       + (size_t)8 * 512 * 16
                       + 512
                       + (size_t)32 * 4096
                       + (size_t)2 * 896 * 256 / 2 + 64;
  int NB = 8;
  while (NB > 1) {
    if ((perb_f * (size_t)NB + fixed_f) * 4 <= ws_size) break;
    NB >>= 1;
  }

  float* ws = (float*)d_ws;
  size_t off = 0;
  float* qkvraw = ws + off; off += (size_t)NB * D3_ * HWs;
  float* g1     = ws + off; off += (size_t)NB * 128 * HWs;
  float* uni    = ws + off; off += (size_t)NB * 512 * HWs;
  float* S_part = ws + off; off += (size_t)32 * 32 * 4096;
  float* S      = ws + off; off += (size_t)32 * 4096;
  float* ssqp   = ws + off; off += (size_t)8 * 512 * 16;
  float* gpart  = ws + off; off += 512;
  float* attnb  = ws + off; off += (size_t)32 * 4096;
  ushort_t* WH  = (ushort_t*)(ws + off);
  ushort_t* WL  = WH + (size_t)896 * 256;

  k0_wsplit<<<dim3(896), 256, 0, stream>>>(wqkv, gw1, WH, WL);

  for (int g = 0; g < B_ / NB; ++g) {
    const int bbase = g * NB;
    k0_xt<<<dim3(512, 8, NB), 256, 0, stream>>>(x, uni, bbase);
    k1_mfma<<<dim3(128, 7, NB), 256, 0, stream>>>(WH, WL, uni, gb1, qkvraw, g1);
    k2_gate<<<dim3(64, NB, 1), 256, 0, stream>>>(g1, gw2, gb2, gpart, bbase);
    k3a_dw<<<dim3(16, 768, NB), 256, 0, stream>>>(qkvraw, wdw, uni, out, ssqp, bbase);
    k3b_gram<<<dim3(32, 4, NB), 256, 0, stream>>>(uni, S_part, bbase);
  }
  k3c_reduce<<<dim3(16, 32), 256, 0, stream>>>(S_part, S);
  k4_final<<<dim3(32), 256, 0, stream>>>(S, ssqp, gpart, temp, a1, a2, a3, a4, attnb);
  k5_av<<<dim3(128, 4, 8), 256, 0, stream>>>(attnb, out);
}

// Round 5
// 835.214 us; speedup vs baseline: 1.8877x; 1.0162x over previous
//
#include <hip/hip_runtime.h>
#include <hip/hip_bf16.h>
#include <cmath>

#define HW_ 16384
#define IMG_W 128
#define IMG_H 128
#define DIM_ 256
#define D3_ 768
#define HEADS_ 4
#define C_ 64
#define B_ 8

typedef unsigned short ushort_t;
typedef __attribute__((ext_vector_type(8))) short short8v;
typedef __attribute__((ext_vector_type(16))) float f32x16;

#define GLL16(gp, lp) __builtin_amdgcn_global_load_lds( \
    (const __attribute__((address_space(1))) void*)(gp), \
    (__attribute__((address_space(3))) void*)(lp), 16, 0, 0)

static __device__ __forceinline__ ushort_t f2bf_bits(float v) {
  __hip_bfloat16 h = __float2bfloat16(v);
  return *reinterpret_cast<ushort_t*>(&h);
}
static __device__ __forceinline__ float bf2f(ushort_t u) {
  return __uint_as_float(((unsigned int)u) << 16);
}

// ---------------------------------------------------------------------------
// K0a: split W (w_qkv rows 0..767, gw1 rows 768..895) into bf16 hi/lo.
// ---------------------------------------------------------------------------
__global__ __launch_bounds__(256) void k0_wsplit(
    const float* __restrict__ wqkv, const float* __restrict__ gw1,
    ushort_t* __restrict__ WH, ushort_t* __restrict__ WL)
{
  const int row = blockIdx.x;
  const int t = threadIdx.x;
  const float* src = (row < 768) ? (wqkv + (size_t)row * DIM_)
                                 : (gw1 + (size_t)(row - 768) * DIM_);
  const float v = src[t];
  const ushort_t hb = f2bf_bits(v);
  WH[(size_t)row * DIM_ + t] = hb;
  WL[(size_t)row * DIM_ + t] = f2bf_bits(v - bf2f(hb));
}

// ---------------------------------------------------------------------------
// K0b: transpose+split X[b] [256][16384] -> XtH/XtL [16384][256] bf16.
// Xt lives in the per-slot union region (later overwritten by qdw/kdw fp32).
// ---------------------------------------------------------------------------
__global__ __launch_bounds__(256) void k0_xt(
    const float* __restrict__ x, float* __restrict__ uni, int bbase)
{
  const int t = threadIdx.x;
  const int s = blockIdx.z;
  const int b = bbase + s;
  ushort_t* XtH = (ushort_t*)(uni + (size_t)s * 512 * HW_);
  ushort_t* XtL = XtH + (size_t)DIM_ * HW_;
  const int p0 = blockIdx.x * 32, c0 = blockIdx.y * 32;
  const int tx = t & 31, ty = t >> 5;

  __shared__ float sm[32][33];
#pragma unroll
  for (int i = 0; i < 4; ++i) {
    const int c = c0 + ty + i * 8;
    sm[ty + i * 8][tx] = x[((size_t)b * DIM_ + c) * HW_ + p0 + tx];
  }
  __syncthreads();
#pragma unroll
  for (int i = 0; i < 4; ++i) {
    const int p = p0 + ty + i * 8;
    const float v = sm[tx][ty + i * 8];
    const ushort_t hb = f2bf_bits(v);
    XtH[(size_t)p * DIM_ + c0 + tx] = hb;
    XtL[(size_t)p * DIM_ + c0 + tx] = f2bf_bits(v - bf2f(hb));
  }
}

// ---------------------------------------------------------------------------
// K1: MFMA GEMM (bf16 hi/lo, 3 MFMA/product), 2-phase double-buffered.
// BK=32, two 32KB LDS buffers; STAGE(next) issued before compute(cur);
// one barrier per K-step. Rows 0..767 -> qkvraw; rows 768..895 ->
// fused gate: relu(.+gb1) . gw2 -> sigmoid -> per-(b,cb) partial sum.
// ---------------------------------------------------------------------------
__global__ __launch_bounds__(256, 2) void k1_mfma(
    const ushort_t* __restrict__ WH, const ushort_t* __restrict__ WL,
    const float* __restrict__ uni, const float* __restrict__ gb1,
    const float* __restrict__ gw2, const float* __restrict__ gb2,
    float* __restrict__ qkvraw, float* __restrict__ gpart, int bbase)
{
  const int t = threadIdx.x;
  const int cb = blockIdx.x, rb = blockIdx.y, s = blockIdx.z;
  const int row0 = rb * 128, col0 = cb * 128;
  const ushort_t* XtH = (const ushort_t*)(uni + (size_t)s * 512 * HW_);
  const ushort_t* XtL = XtH + (size_t)DIM_ * HW_;

  // [parity 2][array 4: AH AL BH BL][4096 shorts = 8KB]
  __shared__ __align__(16) ushort_t lds[2 * 4 * 4096];  // 64 KB

  const int lane = t & 63, wid = t >> 6;
  const int wm = wid >> 1, wn = wid & 1;
  const int rr = lane & 31, lh = lane >> 5;

  const size_t arowb = (size_t)(row0 + wid * 32 + rr) * DIM_;
  const size_t prowb = (size_t)(col0 + wid * 32 + rr) * DIM_;

  f32x16 acc[2][2];
#pragma unroll
  for (int mi = 0; mi < 2; ++mi)
#pragma unroll
    for (int ni = 0; ni < 2; ++ni)
#pragma unroll
      for (int r = 0; r < 16; ++r) acc[mi][ni][r] = 0.f;

  auto STAGE = [&](int pb, int k0) {
    ushort_t* base = lds + pb * 16384;
#pragma unroll
    for (int i = 0; i < 2; ++i) {
      const int koff = k0 + i * 16 + lh * 8;
      ushort_t* dst = base + (wid * 2 + i) * 512;  // wave-uniform
      GLL16(WH + arowb + koff, dst);
      GLL16(WL + arowb + koff, dst + 4096);
      GLL16(XtH + prowb + koff, dst + 8192);
      GLL16(XtL + prowb + koff, dst + 12288);
    }
  };

  STAGE(0, 0);
  __syncthreads();

  for (int kt = 0; kt < 8; ++kt) {
    const int pb = kt & 1;
    if (kt < 7) STAGE(pb ^ 1, (kt + 1) * 32);
    const ushort_t* pAH = lds + pb * 16384;
    const ushort_t* pAL = pAH + 4096;
    const ushort_t* pBH = pAH + 8192;
    const ushort_t* pBL = pAH + 12288;
    const int lo = lane * 8;
#pragma unroll
    for (int ks = 0; ks < 2; ++ks) {
      short8v ah[2], al[2], bh[2], bl[2];
#pragma unroll
      for (int mi = 0; mi < 2; ++mi) {
        const int base = (wm * 2 + mi) * 1024 + ks * 512 + lo;
        ah[mi] = *(const short8v*)(pAH + base);
        al[mi] = *(const short8v*)(pAL + base);
      }
#pragma unroll
      for (int ni = 0; ni < 2; ++ni) {
        const int base = (wn * 2 + ni) * 1024 + ks * 512 + lo;
        bh[ni] = *(const short8v*)(pBH + base);
        bl[ni] = *(const short8v*)(pBL + base);
      }
#pragma unroll
      for (int mi = 0; mi < 2; ++mi)
#pragma unroll
        for (int ni = 0; ni < 2; ++ni) {
          acc[mi][ni] = __builtin_amdgcn_mfma_f32_32x32x16_bf16(
              ah[mi], bh[ni], acc[mi][ni], 0, 0, 0);
          acc[mi][ni] = __builtin_amdgcn_mfma_f32_32x32x16_bf16(
              ah[mi], bl[ni], acc[mi][ni], 0, 0, 0);
          acc[mi][ni] = __builtin_amdgcn_mfma_f32_32x32x16_bf16(
              al[mi], bh[ni], acc[mi][ni], 0, 0, 0);
        }
    }
    __syncthreads();
  }

  // Epilogue. C/D layout: col=lane&31, row=(reg&3)+8*(reg>>2)+4*(lane>>5)
  const int cl = lane & 31;
  if (rb < 6) {
#pragma unroll
    for (int mi = 0; mi < 2; ++mi)
#pragma unroll
      for (int ni = 0; ni < 2; ++ni) {
        const int p = col0 + wn * 64 + ni * 32 + cl;
#pragma unroll
        for (int r = 0; r < 16; ++r) {
          const int row = (r & 3) + 8 * (r >> 2) + 4 * lh;
          const int m = row0 + wm * 64 + mi * 32 + row;
          qkvraw[((size_t)s * D3_ + m) * HW_ + p] = acc[mi][ni][r];
        }
      }
  } else {
    // fused gate: per-pixel sv = sum_c relu(acc+gb1[c]) * gw2[c]
    float ps0 = 0.f, ps1 = 0.f;
#pragma unroll
    for (int mi = 0; mi < 2; ++mi)
#pragma unroll
      for (int r = 0; r < 16; ++r) {
        const int row = (r & 3) + 8 * (r >> 2) + 4 * lh;
        const int gr = wm * 64 + mi * 32 + row;
        const float wv = gw2[gr];
        const float bb = gb1[gr];
        ps0 += fmaxf(acc[mi][0][r] + bb, 0.f) * wv;
        ps1 += fmaxf(acc[mi][1][r] + bb, 0.f) * wv;
      }
    ps0 += __shfl_xor(ps0, 32, 64);
    ps1 += __shfl_xor(ps1, 32, 64);
    float* sred = (float*)lds;   // safe: all LDS reads drained by loop barrier
    float* red2 = sred + 256;
    if (lh == 0) {
      sred[wid * 64 + cl] = ps0;
      sred[wid * 64 + 32 + cl] = ps1;
    }
    __syncthreads();
    float sig = 0.f;
    if (t < 128) {
      const int wnp = t >> 6, nip = (t >> 5) & 1, clp = t & 31;
      const float sv = sred[wnp * 64 + nip * 32 + clp]
                     + sred[(wnp + 2) * 64 + nip * 32 + clp] + gb2[0];
      sig = 1.f / (1.f + expf(-sv));
    }
    __syncthreads();
    red2[t] = sig;
    __syncthreads();
    for (int o = 128; o > 0; o >>= 1) {
      if (t < o) red2[t] += red2[t + o];
      __syncthreads();
    }
    if (t == 0) gpart[(size_t)(bbase + s) * 128 + cb] = red2[0];
  }
}

// ---------------------------------------------------------------------------
// K3a: depthwise 3x3 (SAME zero pad). q,k -> fp32 qdw/kdw (+ ssq partials);
// v -> fp32 to d_out.
// ---------------------------------------------------------------------------
__global__ __launch_bounds__(256) void k3a_dw(
    const float* __restrict__ qkvraw, const float* __restrict__ wdw,
    float* __restrict__ uni, float* __restrict__ vout,
    float* __restrict__ ssq_part, int bbase)
{
  const int t = threadIdx.x;
  const int ytile = blockIdx.x;
  const int ch = blockIdx.y;
  const int s = blockIdx.z;
  const int b = bbase + s;
  const int y0 = ytile * 8;
  float* qdw = uni + (size_t)s * 512 * HW_;
  float* kdw = qdw + (size_t)DIM_ * HW_;

  __shared__ float sm[10][130];
  const float* in = qkvraw + ((size_t)s * D3_ + ch) * HW_;
  for (int i = t; i < 1300; i += 256) {
    const int r = i / 130;
    const int xx = i - r * 130 - 1;
    const int row = y0 - 1 + r;
    float v = 0.f;
    if (row >= 0 && row < IMG_H && xx >= 0 && xx < IMG_W)
      v = in[row * IMG_W + xx];
    sm[r][i - r * 130] = v;
  }
  const float* wp = wdw + ch * 9;
  const float w00 = wp[0], w01 = wp[1], w02 = wp[2],
              w10 = wp[3], w11 = wp[4], w12 = wp[5],
              w20 = wp[6], w21 = wp[7], w22 = wp[8];
  __syncthreads();

  float* outp;
  if (ch < 256)       outp = qdw + (size_t)ch * HW_;
  else if (ch < 512)  outp = kdw + (size_t)(ch - 256) * HW_;
  else                outp = vout + ((size_t)b * DIM_ + (ch - 512)) * HW_;

  float sq = 0.f;
#pragma unroll
  for (int it = 0; it < 4; ++it) {
    const int px = t + it * 256;
    const int yl = px >> 7, xx = px & 127;
    const float a =
      w00 * sm[yl][xx]     + w01 * sm[yl][xx + 1]     + w02 * sm[yl][xx + 2] +
      w10 * sm[yl + 1][xx] + w11 * sm[yl + 1][xx + 1] + w12 * sm[yl + 1][xx + 2] +
      w20 * sm[yl + 2][xx] + w21 * sm[yl + 2][xx + 1] + w22 * sm[yl + 2][xx + 2];
    outp[y0 * IMG_W + px] = a;
    sq += a * a;
  }

  if (ch < 512) {
    __shared__ float red[256];
    red[t] = sq;
    __syncthreads();
    for (int o = 128; o > 0; o >>= 1) {
      if (t < o) red[t] += red[t + o];
      __syncthreads();
    }
    if (t == 0) ssq_part[((size_t)b * 512 + ch) * 16 + ytile] = red[0];
  }
}

// ---------------------------------------------------------------------------
// K3b: Gram partials over 512-pixel chunks (32 chunks per b,h), fp32 input.
// ---------------------------------------------------------------------------
__global__ __launch_bounds__(256) void k3b_gram(
    const float* __restrict__ uni, float* __restrict__ S_part, int bbase)
{
  const int t = threadIdx.x;
  const int chunk = blockIdx.x;  // 0..31
  const int h = blockIdx.y;
  const int s = blockIdx.z;
  const int b = bbase + s;
  const int p0 = chunk * 512;
  const float* qdw = uni + (size_t)s * 512 * HW_;
  const float* kdw = qdw + (size_t)DIM_ * HW_;

  __shared__ float qs[64][68];
  __shared__ float ks[64][68];

  const int rc = t >> 4, dc = t & 15;

  float acc[4][4];
#pragma unroll
  for (int i = 0; i < 4; ++i)
#pragma unroll
    for (int j = 0; j < 4; ++j) acc[i][j] = 0.f;

  const float* qbase = qdw + (size_t)h * 64 * HW_ + p0;
  const float* kbase = kdw + (size_t)h * 64 * HW_ + p0;

  for (int kk = 0; kk < 512; kk += 64) {
    __syncthreads();
#pragma unroll
    for (int j = 0; j < 4; ++j) {
      const int lin = t + j * 256;
      const int c = lin >> 4;
      const int px0 = (lin & 15) << 2;
      const float4 qv = *(const float4*)(qbase + (size_t)c * HW_ + kk + px0);
      const float4 kv = *(const float4*)(kbase + (size_t)c * HW_ + kk + px0);
      qs[px0 + 0][c] = qv.x; qs[px0 + 1][c] = qv.y;
      qs[px0 + 2][c] = qv.z; qs[px0 + 3][c] = qv.w;
      ks[px0 + 0][c] = kv.x; ks[px0 + 1][c] = kv.y;
      ks[px0 + 2][c] = kv.z; ks[px0 + 3][c] = kv.w;
    }
    __syncthreads();
#pragma unroll 4
    for (int p = 0; p < 64; ++p) {
      const float4 q4 = *(const float4*)&qs[p][rc * 4];
      const float4 k4 = *(const float4*)&ks[p][dc * 4];
      const float qa[4] = {q4.x, q4.y, q4.z, q4.w};
      const float ka[4] = {k4.x, k4.y, k4.z, k4.w};
#pragma unroll
      for (int i = 0; i < 4; ++i)
#pragma unroll
        for (int jj = 0; jj < 4; ++jj) acc[i][jj] += qa[i] * ka[jj];
    }
  }
  float* op = S_part + (((size_t)(b * HEADS_ + h)) * 32 + chunk) * 4096;
#pragma unroll
  for (int i = 0; i < 4; ++i) {
    float4 v;
    v.x = acc[i][0]; v.y = acc[i][1]; v.z = acc[i][2]; v.w = acc[i][3];
    *(float4*)(op + (rc * 4 + i) * 64 + dc * 4) = v;
  }
}

// ---------------------------------------------------------------------------
// K3c: parallel reduce S_part[32 chunks] -> S. Fully coalesced.
// ---------------------------------------------------------------------------
__global__ __launch_bounds__(256) void k3c_reduce(
    const float* __restrict__ S_part, float* __restrict__ S)
{
  const int t = threadIdx.x;
  const int bh = blockIdx.y;
  const int e = blockIdx.x * 256 + t;
  float sum = 0.f;
#pragma unroll 8
  for (int c = 0; c < 32; ++c)
    sum += S_part[((size_t)bh * 32 + c) * 4096 + e];
  S[(size_t)bh * 4096 + e] = sum;
}

// ---------------------------------------------------------------------------
// K4: finalize attention. 256 threads (4 waves) per (b,h).
// ---------------------------------------------------------------------------
__global__ __launch_bounds__(256) void k4_final(
    const float* __restrict__ S, const float* __restrict__ ssq_part,
    const float* __restrict__ gpart, const float* __restrict__ temperature,
    const float* __restrict__ a1, const float* __restrict__ a2,
    const float* __restrict__ a3, const float* __restrict__ a4,
    float* __restrict__ attn)
{
  const int t = threadIdx.x;
  const int lane = t & 63, w = t >> 6;
  const int bh = blockIdx.x;
  const int b = bh >> 2, h = bh & 3;

  __shared__ float red[256];
  __shared__ float invq[64], invk[64];

  red[t] = gpart[t] + gpart[t + 256] + gpart[t + 512] + gpart[t + 768];
  __syncthreads();
  for (int o = 128; o > 0; o >>= 1) {
    if (t < o) red[t] += red[t + o];
    __syncthreads();
  }
  const float mean = red[0] / (float)((size_t)B_ * HW_);
  int dk = (int)floorf((float)C_ * mean);
  dk = min(max(dk, 1), 64);

  if (t < 128) {
    const int d = t & 63;
    const int ch = (t < 64 ? 0 : 256) + h * 64 + d;
    const float* pp = ssq_part + ((size_t)b * 512 + ch) * 16;
    float sv = 0.f;
#pragma unroll
    for (int yt = 0; yt < 16; ++yt) sv += pp[yt];
    const float inv = 1.f / fmaxf(sqrtf(sv), 1e-12f);
    if (t < 64) invq[d] = inv; else invk[d] = inv;
  }
  __syncthreads();

  const float tval = temperature[h];
  const float ascale = a1[0] + a2[0] + a3[0] + a4[0];
  const float* Sp = S + (size_t)bh * 4096;
  float* op = attn + (size_t)bh * 4096;

  for (int i = 0; i < 16; ++i) {
    const int c = w * 16 + i;
    const float val = Sp[c * 64 + lane] * invq[c] * invk[lane] * tval;
    int rank = 0;
    for (int j = 0; j < 64; ++j) {
      const float vj = __shfl(val, j, 64);
      rank += ((vj > val) || (vj == val && j < lane)) ? 1 : 0;
    }
    const bool keep = rank < dk;
    float mv = keep ? val : -INFINITY;
#pragma unroll
    for (int m = 1; m < 64; m <<= 1) mv = fmaxf(mv, __shfl_xor(mv, m, 64));
    const float e = keep ? expf(val - mv) : 0.f;
    float ssum = e;
#pragma unroll
    for (int m = 1; m < 64; m <<= 1) ssum += __shfl_xor(ssum, m, 64);
    op[c * 64 + lane] = (e / ssum) * ascale;
  }
}

// ---------------------------------------------------------------------------
// K5: out = attn @ v in place on d_out. LDS-staged v tile [64][128] + attn.
// ---------------------------------------------------------------------------
__global__ __launch_bounds__(256) void k5_av(
    const float* __restrict__ attn, float* __restrict__ out)
{
  const int t = threadIdx.x;
  const int pc = blockIdx.x;  // 0..127
  const int h = blockIdx.y;
  const int b = blockIdx.z;
  const int p0 = pc * 128;

  __shared__ float vs[64][128];   // 32 KB
  __shared__ float As5[64][64];   // 16 KB

  const float* ap = attn + ((size_t)(b * HEADS_ + h)) * 4096;
  float* As5f = &As5[0][0];
#pragma unroll
  for (int j = 0; j < 4; ++j) {
    const int idx = t * 4 + j * 1024;
    *(float4*)&As5f[idx] = *(const float4*)(ap + idx);
  }

  float* base = out + ((size_t)b * DIM_ + h * 64) * HW_ + p0;
#pragma unroll
  for (int k = 0; k < 8; ++k) {
    const int fi = (t + k * 256) * 4;
    const int r = fi >> 7, c = fi & 127;
    *(float4*)&vs[r][c] = *(const float4*)(base + (size_t)r * HW_ + c);
  }
  __syncthreads();

  const int px4 = (t & 31) * 4;
  const int ch0 = (t >> 5) * 8;

  float4 acc[8];
#pragma unroll
  for (int ci = 0; ci < 8; ++ci) acc[ci] = make_float4(0.f, 0.f, 0.f, 0.f);

#pragma unroll 4
  for (int d = 0; d < 64; ++d) {
    const float4 v4 = *(const float4*)&vs[d][px4];
#pragma unroll
    for (int ci = 0; ci < 8; ++ci) {
      const float a = As5[ch0 + ci][d];
      acc[ci].x = fmaf(a, v4.x, acc[ci].x);
      acc[ci].y = fmaf(a, v4.y, acc[ci].y);
      acc[ci].z = fmaf(a, v4.z, acc[ci].z);
      acc[ci].w = fmaf(a, v4.w, acc[ci].w);
    }
  }

#pragma unroll
  for (int ci = 0; ci < 8; ++ci)
    *(float4*)(base + (size_t)(ch0 + ci) * HW_ + px4) = acc[ci];
}

// ---------------------------------------------------------------------------
extern "C" void kernel_launch(void* const* d_in, const int* in_sizes, int n_in,
                              void* d_out, int out_size, void* d_ws, size_t ws_size,
                              hipStream_t stream)
{
  const float* x    = (const float*)d_in[0];
  const float* wqkv = (const float*)d_in[1];
  const float* wdw  = (const float*)d_in[2];
  const float* temp = (const float*)d_in[3];
  const float* a1   = (const float*)d_in[4];
  const float* a2   = (const float*)d_in[5];
  const float* a3   = (const float*)d_in[6];
  const float* a4   = (const float*)d_in[7];
  const float* gw1  = (const float*)d_in[8];
  const float* gb1  = (const float*)d_in[9];
  const float* gw2  = (const float*)d_in[10];
  const float* gb2  = (const float*)d_in[11];
  float* out = (float*)d_out;
  (void)in_sizes; (void)n_in; (void)out_size;

  const size_t HWs = (size_t)HW_;
  // per-slot: qkvraw (768 f) + union[Xt bf16 (256 f) | qdw,kdw fp32 (512 f)]
  const size_t perb_f = (size_t)1280 * HWs;
  const size_t fixed_f = (size_t)32 * 32 * 4096
                       + (size_t)32 * 4096
                       + (size_t)8 * 512 * 16
                       + 1024
                       + (size_t)32 * 4096
                       + (size_t)2 * 896 * 256 / 2 + 64;
  int NB = 8;
  while (NB > 1) {
    if ((perb_f * (size_t)NB + fixed_f) * 4 <= ws_size) break;
    NB >>= 1;
  }

  float* ws = (float*)d_ws;
  size_t off = 0;
  float* qkvraw = ws + off; off += (size_t)NB * D3_ * HWs;
  float* uni    = ws + off; off += (size_t)NB * 512 * HWs;
  float* S_part = ws + off; off += (size_t)32 * 32 * 4096;
  float* S      = ws + off; off += (size_t)32 * 4096;
  float* ssqp   = ws + off; off += (size_t)8 * 512 * 16;
  float* gpart  = ws + off; off += 1024;
  float* attnb  = ws + off; off += (size_t)32 * 4096;
  ushort_t* WH  = (ushort_t*)(ws + off);
  ushort_t* WL  = WH + (size_t)896 * 256;

  k0_wsplit<<<dim3(896), 256, 0, stream>>>(wqkv, gw1, WH, WL);

  for (int g = 0; g < B_ / NB; ++g) {
    const int bbase = g * NB;
    k0_xt<<<dim3(512, 8, NB), 256, 0, stream>>>(x, uni, bbase);
    k1_mfma<<<dim3(128, 7, NB), 256, 0, stream>>>(WH, WL, uni, gb1, gw2, gb2,
                                                  qkvraw, gpart, bbase);
    k3a_dw<<<dim3(16, 768, NB), 256, 0, stream>>>(qkvraw, wdw, uni, out, ssqp, bbase);
    k3b_gram<<<dim3(32, 4, NB), 256, 0, stream>>>(uni, S_part, bbase);
  }
  k3c_reduce<<<dim3(16, 32), 256, 0, stream>>>(S_part, S);
  k4_final<<<dim3(32), 256, 0, stream>>>(S, ssqp, gpart, temp, a1, a2, a3, a4, attnb);
  k5_av<<<dim3(128, 4, 8), 256, 0, stream>>>(attnb, out);
}